// Round 1
// baseline (99.570 us; speedup 1.0000x reference)
//
#include <hip/hip_runtime.h>
#include <math.h>

// Problem constants
#define NTOK   16384   // B*N = 16*1024
#define CIN_   66      // HID + IN_DIM
#define HID_   64
#define NCH    192     // folded columns: [z(64) | r(64) | c(64)]
#define TPB    32      // tokens per block (2 per thread)
#define KPAD   68      // padded k-stride for [tok][k] LDS tiles (16B-aligned, 2-way banks)

__device__ __forceinline__ float fast_sigmoid(float a) {
    return 1.0f / (1.0f + __expf(-a));
}
__device__ __forceinline__ float fast_tanh(float a) {
    return 1.0f - 2.0f / (__expf(2.0f * a) + 1.0f);
}

// ---------------------------------------------------------------------------
// Single fused kernel. 512 blocks x 256 threads; block owns 32 tokens,
// thread owns 2 tokens x (8 z/r | 4 c) channels.
//
// Weight folding (gconv_rnn source bug => effective weight =
// W[:66] + 0.05*(W[66:132]+W[132:198]); z uses pair (0,1), r (2,3), hc (4,5))
// is done INLINE per block into LDS: 3168 float4 outputs, 6 coalesced
// L2-resident float4 loads each, spread over 256 threads (~13 float4/thread).
// This removes the separate fold kernel, its launch, and the workspace
// round-trip; the K-loop then reads weights via conflict-free broadcast
// ds_read_b128 instead of 198 per-thread global loads (the old latency
// exposure at 2 waves/SIMD occupancy).
//
// k-order remap: knew 0..63 -> orig combined row 2+knew (h), knew 64,65 -> x.
// LDS: Wt1 33.8KB + Wt2 16.9KB + bfs 0.8KB + 3 act tiles 26.1KB = 77.6KB
//   -> 2 blocks/CU (unchanged vs before; grid is 512 = 2/CU anyway).
// ---------------------------------------------------------------------------
__global__ __launch_bounds__(256, 2)
void dgcrm_gru_fused(const float* __restrict__ x,     // [NTOK][2]
                     const float* __restrict__ h,     // [NTOK][64]
                     const float* __restrict__ rnn_W, // [6][198][64]
                     const float* __restrict__ rnn_b, // [6][64]
                     float* __restrict__ out)         // [NTOK][64]
{
    __shared__ float Wt1[16][CIN_][8];  // z|r weights, grp-major
    __shared__ float Wt2[16][CIN_][4];  // hc weights, grp-major
    __shared__ float bfs[NCH];          // folded biases [z|r|c]
    __shared__ float Cs[TPB][KPAD];     // combined: k 0..63 = h, 64..65 = x
    __shared__ float Ds[TPB][KPAD];     // candidate: k 0..63 = r*h, 64..65 = x
    __shared__ float Zs[TPB][KPAD];     // z, then overwritten with output

    const int tid = threadIdx.x;
    const int t0  = blockIdx.x * TPB;

    // ---- stage h: 32 tok x 64 ch = 512 float4, direct [tok][k] b128 writes --
    {
        const float4* h4 = (const float4*)(h + (size_t)t0 * HID_);
        #pragma unroll
        for (int r = 0; r < 2; ++r) {
            int i = tid + r * 256;        // 0..511
            float4 v = h4[i];
            int t = i >> 4;               // token 0..31
            int c = (i * 4) & 63;         // k 0,4,...,60
            *(float4*)&Cs[t][c] = v;
        }
    }
    // ---- stage x into k = 64,65 of Cs and Ds ----
    if (tid < 2 * TPB) {
        int t = tid >> 1, k = tid & 1;
        float v = x[(size_t)(t0 + t) * 2 + k];
        Cs[t][64 + k] = v;
        Ds[t][64 + k] = v;
    }
    // ---- inline weight fold: rnn_W -> Wt1/Wt2 in LDS ----
    // 192 ch x 66 k = 12672 floats = 3168 float4. fid -> (knew, c=4*rem).
    {
        const float4* W4 = (const float4*)rnn_W;
        const float s = 0.05f;
        #pragma unroll 2
        for (int it = 0; it < 13; ++it) {
            int fid = tid + it * 256;
            if (fid < 3168) {
                int knew = fid / 48;             // const divisor -> magic mul
                int rem  = fid - knew * 48;
                int c    = rem * 4;              // channel base 0..188
                int korig = (knew < 64) ? (knew + 2) : (knew - 64);
                int g  = c >> 6;                 // gate 0:z 1:r 2:c
                int j4 = (c & 63) >> 2;          // float4 col within 64-row
                int i0 = 2 * g, i1 = 2 * g + 1;
                float4 a0 = W4[(i0 * 198 + korig      ) * 16 + j4];
                float4 a1 = W4[(i0 * 198 +  66 + korig) * 16 + j4];
                float4 a2 = W4[(i0 * 198 + 132 + korig) * 16 + j4];
                float4 b0 = W4[(i1 * 198 + korig      ) * 16 + j4];
                float4 b1 = W4[(i1 * 198 +  66 + korig) * 16 + j4];
                float4 b2 = W4[(i1 * 198 + 132 + korig) * 16 + j4];
                float4 v;
                v.x = a0.x + b0.x + s * ((a1.x + a2.x) + (b1.x + b2.x));
                v.y = a0.y + b0.y + s * ((a1.y + a2.y) + (b1.y + b2.y));
                v.z = a0.z + b0.z + s * ((a1.z + a2.z) + (b1.z + b2.z));
                v.w = a0.w + b0.w + s * ((a1.w + a2.w) + (b1.w + b2.w));
                if (c < 128) {
                    // grp = c>>3, jj = c&7 in {0,4} -> 16B-aligned slot
                    *(float4*)&Wt1[c >> 3][knew][c & 7] = v;
                } else {
                    *(float4*)&Wt2[(c - 128) >> 2][knew][0] = v;
                }
            }
        }
        if (tid < NCH) {
            int g = tid >> 6, j = tid & 63;
            bfs[tid] = rnn_b[(2 * g) * 64 + j] + rnn_b[(2 * g + 1) * 64 + j];
        }
    }
    __syncthreads();

    const int grp  = tid >> 4;   // 0..15 channel group
    const int tokA = tid & 15;
    const int tokB = tokA + 16;

    // =================== phase 1: z (ch 0..63) and r (ch 64..127) ==========
    {
        const int ch0 = grp * 8;
        const float* wp = &Wt1[grp][0][0];
        float accA[8], accB[8];
        {
            float4 b0 = *(const float4*)(bfs + ch0);
            float4 b1 = *(const float4*)(bfs + ch0 + 4);
            accA[0] = b0.x; accA[1] = b0.y; accA[2] = b0.z; accA[3] = b0.w;
            accA[4] = b1.x; accA[5] = b1.y; accA[6] = b1.z; accA[7] = b1.w;
            #pragma unroll
            for (int j = 0; j < 8; ++j) accB[j] = accA[j];
        }
        #pragma unroll
        for (int kb = 0; kb < 16; ++kb) {
            float4 a4 = *(const float4*)&Cs[tokA][4 * kb];
            float4 b4 = *(const float4*)&Cs[tokB][4 * kb];
            float ca[4] = {a4.x, a4.y, a4.z, a4.w};
            float cb[4] = {b4.x, b4.y, b4.z, b4.w};
            #pragma unroll
            for (int j = 0; j < 4; ++j) {
                float4 w0 = *(const float4*)(wp + (4 * kb + j) * 8);
                float4 w1 = *(const float4*)(wp + (4 * kb + j) * 8 + 4);
                accA[0] = fmaf(ca[j], w0.x, accA[0]);  accB[0] = fmaf(cb[j], w0.x, accB[0]);
                accA[1] = fmaf(ca[j], w0.y, accA[1]);  accB[1] = fmaf(cb[j], w0.y, accB[1]);
                accA[2] = fmaf(ca[j], w0.z, accA[2]);  accB[2] = fmaf(cb[j], w0.z, accB[2]);
                accA[3] = fmaf(ca[j], w0.w, accA[3]);  accB[3] = fmaf(cb[j], w0.w, accB[3]);
                accA[4] = fmaf(ca[j], w1.x, accA[4]);  accB[4] = fmaf(cb[j], w1.x, accB[4]);
                accA[5] = fmaf(ca[j], w1.y, accA[5]);  accB[5] = fmaf(cb[j], w1.y, accB[5]);
                accA[6] = fmaf(ca[j], w1.z, accA[6]);  accB[6] = fmaf(cb[j], w1.z, accB[6]);
                accA[7] = fmaf(ca[j], w1.w, accA[7]);  accB[7] = fmaf(cb[j], w1.w, accB[7]);
            }
        }
        // tail k = 64, 65 (x rows)
        {
            float a64 = Cs[tokA][64], a65 = Cs[tokA][65];
            float b64 = Cs[tokB][64], b65 = Cs[tokB][65];
            float4 u0 = *(const float4*)(wp + 64 * 8);
            float4 u1 = *(const float4*)(wp + 64 * 8 + 4);
            float4 v0 = *(const float4*)(wp + 65 * 8);
            float4 v1 = *(const float4*)(wp + 65 * 8 + 4);
            float wu[8] = {u0.x,u0.y,u0.z,u0.w,u1.x,u1.y,u1.z,u1.w};
            float wv[8] = {v0.x,v0.y,v0.z,v0.w,v1.x,v1.y,v1.z,v1.w};
            #pragma unroll
            for (int j = 0; j < 8; ++j) {
                accA[j] = fmaf(a64, wu[j], fmaf(a65, wv[j], accA[j]));
                accB[j] = fmaf(b64, wu[j], fmaf(b65, wv[j], accB[j]));
            }
        }
        if (grp < 8) {
            float4 za0, za1, zb0, zb1;
            za0.x = fast_sigmoid(accA[0]); za0.y = fast_sigmoid(accA[1]);
            za0.z = fast_sigmoid(accA[2]); za0.w = fast_sigmoid(accA[3]);
            za1.x = fast_sigmoid(accA[4]); za1.y = fast_sigmoid(accA[5]);
            za1.z = fast_sigmoid(accA[6]); za1.w = fast_sigmoid(accA[7]);
            zb0.x = fast_sigmoid(accB[0]); zb0.y = fast_sigmoid(accB[1]);
            zb0.z = fast_sigmoid(accB[2]); zb0.w = fast_sigmoid(accB[3]);
            zb1.x = fast_sigmoid(accB[4]); zb1.y = fast_sigmoid(accB[5]);
            zb1.z = fast_sigmoid(accB[6]); zb1.w = fast_sigmoid(accB[7]);
            *(float4*)&Zs[tokA][ch0]     = za0;
            *(float4*)&Zs[tokA][ch0 + 4] = za1;
            *(float4*)&Zs[tokB][ch0]     = zb0;
            *(float4*)&Zs[tokB][ch0 + 4] = zb1;
        } else {
            const int rb = ch0 - 64;     // 0..56
            float4 ha0 = *(const float4*)&Cs[tokA][rb];
            float4 ha1 = *(const float4*)&Cs[tokA][rb + 4];
            float4 hb0 = *(const float4*)&Cs[tokB][rb];
            float4 hb1 = *(const float4*)&Cs[tokB][rb + 4];
            float4 da0, da1, db0, db1;
            da0.x = fast_sigmoid(accA[0]) * ha0.x;  da0.y = fast_sigmoid(accA[1]) * ha0.y;
            da0.z = fast_sigmoid(accA[2]) * ha0.z;  da0.w = fast_sigmoid(accA[3]) * ha0.w;
            da1.x = fast_sigmoid(accA[4]) * ha1.x;  da1.y = fast_sigmoid(accA[5]) * ha1.y;
            da1.z = fast_sigmoid(accA[6]) * ha1.z;  da1.w = fast_sigmoid(accA[7]) * ha1.w;
            db0.x = fast_sigmoid(accB[0]) * hb0.x;  db0.y = fast_sigmoid(accB[1]) * hb0.y;
            db0.z = fast_sigmoid(accB[2]) * hb0.z;  db0.w = fast_sigmoid(accB[3]) * hb0.w;
            db1.x = fast_sigmoid(accB[4]) * hb1.x;  db1.y = fast_sigmoid(accB[5]) * hb1.y;
            db1.z = fast_sigmoid(accB[6]) * hb1.z;  db1.w = fast_sigmoid(accB[7]) * hb1.w;
            *(float4*)&Ds[tokA][rb]     = da0;
            *(float4*)&Ds[tokA][rb + 4] = da1;
            *(float4*)&Ds[tokB][rb]     = db0;
            *(float4*)&Ds[tokB][rb + 4] = db1;
        }
    }
    __syncthreads();

    // =================== phase 2: hc (ch 128..191), combine ================
    {
        const int c0 = 128 + grp * 4;    // bias index
        const float* wp = &Wt2[grp][0][0];
        float accA[4], accB[4];
        {
            float4 b0 = *(const float4*)(bfs + c0);
            accA[0] = b0.x; accA[1] = b0.y; accA[2] = b0.z; accA[3] = b0.w;
            #pragma unroll
            for (int j = 0; j < 4; ++j) accB[j] = accA[j];
        }
        #pragma unroll
        for (int kb = 0; kb < 16; ++kb) {
            float4 a4 = *(const float4*)&Ds[tokA][4 * kb];
            float4 b4 = *(const float4*)&Ds[tokB][4 * kb];
            float ca[4] = {a4.x, a4.y, a4.z, a4.w};
            float cb[4] = {b4.x, b4.y, b4.z, b4.w};
            #pragma unroll
            for (int j = 0; j < 4; ++j) {
                float4 w = *(const float4*)(wp + (4 * kb + j) * 4);
                accA[0] = fmaf(ca[j], w.x, accA[0]);  accB[0] = fmaf(cb[j], w.x, accB[0]);
                accA[1] = fmaf(ca[j], w.y, accA[1]);  accB[1] = fmaf(cb[j], w.y, accB[1]);
                accA[2] = fmaf(ca[j], w.z, accA[2]);  accB[2] = fmaf(cb[j], w.z, accB[2]);
                accA[3] = fmaf(ca[j], w.w, accA[3]);  accB[3] = fmaf(cb[j], w.w, accB[3]);
            }
        }
        // tail k = 64, 65 (x rows)
        {
            float a64 = Ds[tokA][64], a65 = Ds[tokA][65];
            float b64 = Ds[tokB][64], b65 = Ds[tokB][65];
            float4 u = *(const float4*)(wp + 64 * 4);
            float4 v = *(const float4*)(wp + 65 * 4);
            float wu[4] = {u.x, u.y, u.z, u.w};
            float wv[4] = {v.x, v.y, v.z, v.w};
            #pragma unroll
            for (int j = 0; j < 4; ++j) {
                accA[j] = fmaf(a64, wu[j], fmaf(a65, wv[j], accA[j]));
                accB[j] = fmaf(b64, wu[j], fmaf(b65, wv[j], accB[j]));
            }
        }
        const int hb = grp * 4;          // hc channel base 0..60
        float4 zA = *(const float4*)&Zs[tokA][hb];
        float4 zB = *(const float4*)&Zs[tokB][hb];
        float4 hA = *(const float4*)&Cs[tokA][hb];
        float4 hB = *(const float4*)&Cs[tokB][hb];
        float4 oA, oB;
        oA.x = zA.x * hA.x + (1.0f - zA.x) * fast_tanh(accA[0]);
        oA.y = zA.y * hA.y + (1.0f - zA.y) * fast_tanh(accA[1]);
        oA.z = zA.z * hA.z + (1.0f - zA.z) * fast_tanh(accA[2]);
        oA.w = zA.w * hA.w + (1.0f - zA.w) * fast_tanh(accA[3]);
        oB.x = zB.x * hB.x + (1.0f - zB.x) * fast_tanh(accB[0]);
        oB.y = zB.y * hB.y + (1.0f - zB.y) * fast_tanh(accB[1]);
        oB.z = zB.z * hB.z + (1.0f - zB.z) * fast_tanh(accB[2]);
        oB.w = zB.w * hB.w + (1.0f - zB.w) * fast_tanh(accB[3]);
        *(float4*)&Zs[tokA][hb] = oA;
        *(float4*)&Zs[tokB][hb] = oB;
    }
    __syncthreads();

    // ---- coalesced write-back: out[t][c..c+3] = Zs[t][c..c+3] ----
    {
        float4* o4 = (float4*)(out + (size_t)t0 * HID_);
        #pragma unroll
        for (int r = 0; r < 2; ++r) {
            int i = tid + r * 256;
            int t = i >> 4;
            int c = (i * 4) & 63;
            o4[i] = *(const float4*)&Zs[t][c];
        }
    }
}

// ---------------------------------------------------------------------------
extern "C" void kernel_launch(void* const* d_in, const int* in_sizes, int n_in,
                              void* d_out, int out_size, void* d_ws, size_t ws_size,
                              hipStream_t stream)
{
    const float* x     = (const float*)d_in[0];   // [16,1024,2]
    const float* hprev = (const float*)d_in[1];   // [16,1024,64]
    const float* rnn_W = (const float*)d_in[12];  // [6,198,64]
    const float* rnn_b = (const float*)d_in[13];  // [6,64]

    dgcrm_gru_fused<<<NTOK / TPB, 256, 0, stream>>>(x, hprev, rnn_W, rnn_b,
                                                    (float*)d_out);
}